// Round 8
// baseline (211.717 us; speedup 1.0000x reference)
//
#include <hip/hip_runtime.h>
#include <hip/hip_fp16.h>

#define N_NODES 50000
#define N_EDGES 800000
#define N_GRAPHS 512
#define F_IN 128
#define HDIM 64
#define BSH 7                // 128 nodes per bucket
#define NBUCK 391            // ceil(50000/128)
#define BCAP 2560            // per-bucket staging cap (avg 2048, max ~2250)
#define EPB 2048             // edges per pass-1 block
#define N_P1 ((N_EDGES + EPB - 1) / EPB)   // 391
#define MAXPER 10            // BCAP/256
#define EMAX (N_EDGES - 1)

typedef _Float16 half8 __attribute__((ext_vector_type(8)));
typedef float f32x4 __attribute__((ext_vector_type(4)));

// ---------------- transpose W1,W2 to [col][k] f16 + zero bucket totals ----------------
__global__ __launch_bounds__(256) void twt_k(const float* __restrict__ W1, const float* __restrict__ W2,
                                             _Float16* __restrict__ Wt1, _Float16* __restrict__ Wt2,
                                             int* __restrict__ bTot) {
    int t = threadIdx.x;
    bTot[t] = 0; bTot[t + 256] = 0;
    for (int m = t; m < F_IN * HDIM; m += 256) { int k = m >> 6, c = m & 63; Wt1[c * F_IN + k] = (_Float16)W1[m]; }
    for (int m = t; m < HDIM * HDIM; m += 256) { int k = m >> 6, c = m & 63; Wt2[c * HDIM + k] = (_Float16)W2[m]; }
}

// ---------------- pass 1: bin edges by dst bucket; LDS counting sort -> coalesced writes ----------------
__global__ __launch_bounds__(256) void pass1_k(const int* __restrict__ src, const int* __restrict__ dst,
                                               int* __restrict__ bucketTot, int* __restrict__ stage) {
    __shared__ int cnt[512];
    __shared__ int pfE[512];
    __shared__ int sb[256];
    __shared__ int goff[512];
    __shared__ int lpk[EPB];
    __shared__ unsigned short bkn[EPB];
    int t = threadIdx.x;
    cnt[t] = 0; cnt[t + 256] = 0;
    __syncthreads();
    int base = blockIdx.x * EPB + t * 8;
    int packed[8], bk[8], rk[8];
    bool full = (blockIdx.x + 1) * EPB <= N_EDGES;
    if (full) {
        const int4* s4 = (const int4*)(src + base);
        const int4* d4 = (const int4*)(dst + base);
        #pragma unroll
        for (int q = 0; q < 2; ++q) {
            int4 sv = s4[q], dv = d4[q];
            int ss[4] = {sv.x, sv.y, sv.z, sv.w};
            int dd[4] = {dv.x, dv.y, dv.z, dv.w};
            #pragma unroll
            for (int jj = 0; jj < 4; ++jj) {
                int b = dd[jj] >> BSH;
                rk[q * 4 + jj] = atomicAdd(&cnt[b], 1);
                bk[q * 4 + jj] = b;
                packed[q * 4 + jj] = ss[jj] | ((dd[jj] & 127) << 16);
            }
        }
    } else {
        #pragma unroll
        for (int k = 0; k < 8; ++k) {
            int e = base + k;
            if (e < N_EDGES) {
                int d = dst[e];
                int b = d >> BSH;
                rk[k] = atomicAdd(&cnt[b], 1);
                bk[k] = b;
                packed[k] = src[e] | ((d & 127) << 16);
            } else bk[k] = -1;
        }
    }
    __syncthreads();
    // pair-scan over 512 bucket counters (thread t owns 2t, 2t+1)
    int c0 = cnt[2 * t], c1 = cnt[2 * t + 1];
    int ps = c0 + c1;
    sb[t] = ps; __syncthreads();
    for (int off = 1; off < 256; off <<= 1) {
        int u = (t >= off) ? sb[t - off] : 0; __syncthreads();
        sb[t] += u; __syncthreads();
    }
    int bp = sb[t] - ps;
    pfE[2 * t] = bp; pfE[2 * t + 1] = bp + c0;
    if (c0 > 0) goff[2 * t] = atomicAdd(&bucketTot[2 * t], c0);
    if (c1 > 0) goff[2 * t + 1] = atomicAdd(&bucketTot[2 * t + 1], c1);
    __syncthreads();
    // scatter into bucket-ordered LDS
    #pragma unroll
    for (int k = 0; k < 8; ++k) {
        if (bk[k] >= 0) {
            int b = bk[k];
            int p = pfE[b] + rk[k];
            lpk[p] = packed[k];
            bkn[p] = (unsigned short)b;
        }
    }
    __syncthreads();
    int tot = sb[255];
    // coalesced write-out: consecutive i within a bucket -> consecutive global slots
    for (int i = t; i < tot; i += 256) {
        int b = bkn[i];
        int local = i - pfE[b];
        stage[b * BCAP + goff[b] + local] = lpk[i];
    }
}

// ---------------- pass 2: per-bucket LDS counting sort -> csr, row, dinv (base scan inlined) ----------------
__global__ __launch_bounds__(256) void pass2_k(const int* __restrict__ stage, const int* __restrict__ bucketTot,
                                               int* __restrict__ row, float* __restrict__ dinv,
                                               int* __restrict__ csr) {
    __shared__ int cnt[256];
    __shared__ int pf[256];
    __shared__ int sb[256];
    __shared__ int sbE[512];
    __shared__ int lcsr[BCAP];
    int b = blockIdx.x, t = threadIdx.x;
    int tot = bucketTot[b];
    // inline exclusive scan of 512 bucket totals (zeros beyond NBUCK) for this block's base
    int c0 = bucketTot[2 * t], c1 = bucketTot[2 * t + 1];
    int ps = c0 + c1;
    sb[t] = ps; __syncthreads();
    for (int off = 1; off < 256; off <<= 1) {
        int u = (t >= off) ? sb[t - off] : 0; __syncthreads();
        sb[t] += u; __syncthreads();
    }
    int bp = sb[t] - ps;
    sbE[2 * t] = bp; sbE[2 * t + 1] = bp + c0;
    __syncthreads();
    int base = sbE[b];
    if (b == 0 && t == 0) row[N_NODES] = N_EDGES;
    cnt[t] = 0; __syncthreads();
    int myp[MAXPER], myr[MAXPER];
    #pragma unroll
    for (int k = 0; k < MAXPER; ++k) {
        int i = t + k * 256;
        if (i < tot) {
            int p = stage[b * BCAP + i];
            int loc = (p >> 16) & 255;
            myp[k] = p;
            myr[k] = atomicAdd(&cnt[loc], 1);
        } else myp[k] = -1;
    }
    __syncthreads();
    int cv = cnt[t];
    pf[t] = cv; __syncthreads();
    for (int off = 1; off < 256; off <<= 1) {
        int u = (t >= off) ? pf[t - off] : 0; __syncthreads();
        pf[t] += u; __syncthreads();
    }
    int node = (b << BSH) + t;
    if (t < 128 && node < N_NODES) {
        row[node] = base + pf[t] - cv;
        dinv[node] = rsqrtf((float)cv + 1.0f);
    }
    #pragma unroll
    for (int k = 0; k < MAXPER; ++k) {
        if (myp[k] >= 0) {
            int loc = (myp[k] >> 16) & 255;
            lcsr[pf[loc] - cnt[loc] + myr[k]] = myp[k] & 0xFFFF;
        }
    }
    __syncthreads();
    for (int i = t; i < tot; i += 256) csr[base + i] = lcsr[i];
}

// ---------------- xw1 = (x @ W1) * dinv -> f16 interleaved [N][64], via MFMA ----------------
__global__ __launch_bounds__(256) void xw1_k(const float* __restrict__ x, const _Float16* __restrict__ Wt1,
                                             const float* __restrict__ dinv, _Float16* __restrict__ xwh) {
    __shared__ _Float16 xs[64][136];   // [node][k], pad 8
    __shared__ _Float16 wt[64][136];   // [col][k]
    __shared__ _Float16 outt[64][72];  // [node][col]
    int t = threadIdx.x;
    int row0 = blockIdx.x * 64;
    const float4* x4 = (const float4*)x;
    #pragma unroll
    for (int i = 0; i < 8; ++i) {
        int m = t + i * 256;           // 64 rows x 32 float4
        int n = m >> 5, k4 = m & 31;
        int gn = row0 + n;
        float4 v = make_float4(0.f, 0.f, 0.f, 0.f);
        if (gn < N_NODES) v = x4[gn * 32 + k4];
        _Float16* p = &xs[n][k4 * 4];
        p[0] = (_Float16)v.x; p[1] = (_Float16)v.y; p[2] = (_Float16)v.z; p[3] = (_Float16)v.w;
    }
    const uint4* wt4 = (const uint4*)Wt1;
    #pragma unroll
    for (int i = 0; i < 4; ++i) {
        int m = t + i * 256;           // 64 cols x 16 uint4
        int c = m >> 4, k8 = m & 15;
        *(uint4*)&wt[c][k8 * 8] = wt4[m];
    }
    __syncthreads();
    int w = t >> 6, lane = t & 63, r = lane & 15, q = lane >> 4;
    half8 a[4];
    #pragma unroll
    for (int kk = 0; kk < 4; ++kk) a[kk] = *(const half8*)&xs[w * 16 + r][kk * 32 + q * 8];
    float dv[4];
    #pragma unroll
    for (int reg = 0; reg < 4; ++reg) {
        int n = row0 + w * 16 + q * 4 + reg;
        dv[reg] = (n < N_NODES) ? dinv[n] : 0.f;
    }
    #pragma unroll
    for (int ct = 0; ct < 4; ++ct) {
        f32x4 acc = {0.f, 0.f, 0.f, 0.f};
        #pragma unroll
        for (int kk = 0; kk < 4; ++kk) {
            half8 b = *(const half8*)&wt[ct * 16 + r][kk * 32 + q * 8];
            acc = __builtin_amdgcn_mfma_f32_16x16x32_f16(a[kk], b, acc, 0, 0, 0);
        }
        #pragma unroll
        for (int reg = 0; reg < 4; ++reg)
            outt[w * 16 + q * 4 + reg][ct * 16 + r] = (_Float16)(acc[reg] * dv[reg]);
    }
    __syncthreads();
    #pragma unroll
    for (int i = 0; i < 2; ++i) {
        int m = t + i * 256;           // 64 rows x 8 col-octets
        int n = m >> 3, c8 = m & 7;
        int gn = row0 + n;
        if (gn < N_NODES) {
            uint4 v = *(const uint4*)&outt[n][c8 * 8];
            ((uint4*)xwh)[gn * 8 + c8] = v;
        }
    }
}

// ---------------- xw2 = (h1 @ W2) * dinv -> f16 interleaved, via MFMA ----------------
__global__ __launch_bounds__(256) void conv2_k(const _Float16* __restrict__ h1, const _Float16* __restrict__ Wt2,
                                               const float* __restrict__ dinv, _Float16* __restrict__ xwh) {
    __shared__ _Float16 hs[64][72];
    __shared__ _Float16 wt[64][72];
    __shared__ _Float16 outt[64][72];
    int t = threadIdx.x;
    int row0 = blockIdx.x * 64;
    const uint4* h8 = (const uint4*)h1;
    #pragma unroll
    for (int i = 0; i < 2; ++i) {
        int m = t + i * 256;
        int n = m >> 3, k8 = m & 7;
        int gn = row0 + n;
        uint4 v = make_uint4(0u, 0u, 0u, 0u);
        if (gn < N_NODES) v = h8[gn * 8 + k8];
        *(uint4*)&hs[n][k8 * 8] = v;
    }
    const uint4* wt4 = (const uint4*)Wt2;
    #pragma unroll
    for (int i = 0; i < 2; ++i) {
        int m = t + i * 256;           // 64 cols x 8 uint4
        int c = m >> 3, k8 = m & 7;
        *(uint4*)&wt[c][k8 * 8] = wt4[m];
    }
    __syncthreads();
    int w = t >> 6, lane = t & 63, r = lane & 15, q = lane >> 4;
    half8 a0 = *(const half8*)&hs[w * 16 + r][q * 8];
    half8 a1 = *(const half8*)&hs[w * 16 + r][32 + q * 8];
    float dv[4];
    #pragma unroll
    for (int reg = 0; reg < 4; ++reg) {
        int n = row0 + w * 16 + q * 4 + reg;
        dv[reg] = (n < N_NODES) ? dinv[n] : 0.f;
    }
    #pragma unroll
    for (int ct = 0; ct < 4; ++ct) {
        f32x4 acc = {0.f, 0.f, 0.f, 0.f};
        half8 b0 = *(const half8*)&wt[ct * 16 + r][q * 8];
        half8 b1 = *(const half8*)&wt[ct * 16 + r][32 + q * 8];
        acc = __builtin_amdgcn_mfma_f32_16x16x32_f16(a0, b0, acc, 0, 0, 0);
        acc = __builtin_amdgcn_mfma_f32_16x16x32_f16(a1, b1, acc, 0, 0, 0);
        #pragma unroll
        for (int reg = 0; reg < 4; ++reg)
            outt[w * 16 + q * 4 + reg][ct * 16 + r] = (_Float16)(acc[reg] * dv[reg]);
    }
    __syncthreads();
    #pragma unroll
    for (int i = 0; i < 2; ++i) {
        int m = t + i * 256;
        int n = m >> 3, c8 = m & 7;
        int gn = row0 + n;
        if (gn < N_NODES) {
            uint4 v = *(const uint4*)&outt[n][c8 * 8];
            ((uint4*)xwh)[gn * 8 + c8] = v;
        }
    }
}

// ---------------- gather: h[d] = relu(dinv[d] * (sum xwh[s] + xwh[d]) + b) -> f16 ----------------
__device__ inline void acc8(uint4 v, float* a) {
    float2 f;
    f = __half22float2(__builtin_bit_cast(__half2, v.x)); a[0] += f.x; a[1] += f.y;
    f = __half22float2(__builtin_bit_cast(__half2, v.y)); a[2] += f.x; a[3] += f.y;
    f = __half22float2(__builtin_bit_cast(__half2, v.z)); a[4] += f.x; a[5] += f.y;
    f = __half22float2(__builtin_bit_cast(__half2, v.w)); a[6] += f.x; a[7] += f.y;
}

__global__ __launch_bounds__(256) void gather_k(const _Float16* __restrict__ xwh, const int* __restrict__ row,
                                                const int* __restrict__ csr, const float* __restrict__ dinv,
                                                const float* __restrict__ bias, _Float16* __restrict__ hout) {
    int t = threadIdx.x;
    int node = blockIdx.x * 4 + (t >> 6);
    int lane = t & 63;
    int fq = lane & 7, eslot = lane >> 3;   // 8 feature quads x 8 edge slots (16B/lane, 128B/edge)
    const uint4* xw4 = (const uint4*)xwh;
    float a[8];
    #pragma unroll
    for (int k = 0; k < 8; ++k) a[k] = 0.f;
    if (eslot == 0) acc8(xw4[node * 8 + fq], a);   // self-loop
    int j = row[node] + eslot, jend = row[node + 1];
    // register-prefetched index pipeline: next iteration's csr loads issue
    // before this iteration's data is consumed (breaks idx->data serial chain)
    int s0 = csr[min(j, EMAX)];
    int s1 = csr[min(j + 8, EMAX)];
    for (; j + 8 < jend; j += 16) {
        uint4 v0 = xw4[s0 * 8 + fq];
        uint4 v1 = xw4[s1 * 8 + fq];
        s0 = csr[min(j + 16, EMAX)];
        s1 = csr[min(j + 24, EMAX)];
        acc8(v0, a); acc8(v1, a);
    }
    if (j < jend) acc8(xw4[s0 * 8 + fq], a);
    #pragma unroll
    for (int k = 0; k < 8; ++k) {
        a[k] += __shfl_xor(a[k], 8);
        a[k] += __shfl_xor(a[k], 16);
        a[k] += __shfl_xor(a[k], 32);
    }
    if (eslot == 0) {
        float dd = dinv[node];
        const float4* b4 = (const float4*)bias;
        float4 bl = b4[fq * 2], bh = b4[fq * 2 + 1];
        float r0 = fmaxf(a[0] * dd + bl.x, 0.f), r1 = fmaxf(a[1] * dd + bl.y, 0.f);
        float r2 = fmaxf(a[2] * dd + bl.z, 0.f), r3 = fmaxf(a[3] * dd + bl.w, 0.f);
        float r4 = fmaxf(a[4] * dd + bh.x, 0.f), r5 = fmaxf(a[5] * dd + bh.y, 0.f);
        float r6 = fmaxf(a[6] * dd + bh.z, 0.f), r7 = fmaxf(a[7] * dd + bh.w, 0.f);
        __half2 p0 = __float22half2_rn(make_float2(r0, r1));
        __half2 p1 = __float22half2_rn(make_float2(r2, r3));
        __half2 p2 = __float22half2_rn(make_float2(r4, r5));
        __half2 p3 = __float22half2_rn(make_float2(r6, r7));
        uint4 o;
        o.x = __builtin_bit_cast(unsigned int, p0);
        o.y = __builtin_bit_cast(unsigned int, p1);
        o.z = __builtin_bit_cast(unsigned int, p2);
        o.w = __builtin_bit_cast(unsigned int, p3);
        ((uint4*)hout)[node * 8 + fq] = o;
    }
}

// ---------------- fused mean-pool + MLP ----------------
__device__ inline int lower_bound_i(const int* __restrict__ a, int n, int v) {
    int lo = 0, hi = n;
    while (lo < hi) { int m = (lo + hi) >> 1; if (a[m] < v) lo = m + 1; else hi = m; }
    return lo;
}

__global__ __launch_bounds__(256) void poolmlp_k(const _Float16* __restrict__ h, const int* __restrict__ batch,
                                                 const float* __restrict__ Wf1, const float* __restrict__ bf1,
                                                 const float* __restrict__ Wf2, const float* __restrict__ bf2,
                                                 float* __restrict__ out) {
    __shared__ int se[2];
    __shared__ float red[4][64];
    __shared__ float ps[64];
    __shared__ float wsum[2];
    int g = blockIdx.x, t = threadIdx.x;
    if (t == 0) { se[0] = lower_bound_i(batch, N_NODES, g); se[1] = lower_bound_i(batch, N_NODES, g + 1); }
    __syncthreads();
    int start = se[0], end = se[1];
    int w = t >> 6, lane = t & 63;
    float acc = 0.f;
    for (int n = start + w; n < end; n += 4) acc += (float)h[n * 64 + lane];
    red[w][lane] = acc; __syncthreads();
    if (w == 0) {
        float v = red[0][lane] + red[1][lane] + red[2][lane] + red[3][lane];
        int c = end - start;
        ps[lane] = v / (float)max(c, 1);
    }
    __syncthreads();
    float v = 0.f;
    if (t < 128) {
        float a2 = bf1[t];
        #pragma unroll 8
        for (int k = 0; k < HDIM; ++k) a2 += ps[k] * Wf1[k * 128 + t];
        v = fmaxf(a2, 0.f) * Wf2[t];
        #pragma unroll
        for (int off = 32; off > 0; off >>= 1) v += __shfl_down(v, off);
    }
    if (t == 0) wsum[0] = v;
    if (t == 64) wsum[1] = v;
    __syncthreads();
    if (t == 0) out[g] = wsum[0] + wsum[1] + bf2[0];
}

extern "C" void kernel_launch(void* const* d_in, const int* in_sizes, int n_in,
                              void* d_out, int out_size, void* d_ws, size_t ws_size,
                              hipStream_t stream) {
    const float* x    = (const float*)d_in[0];
    const int*   ei   = (const int*)d_in[1];
    const int*   src  = ei;
    const int*   dst  = ei + N_EDGES;
    const int*   batch= (const int*)d_in[2];
    const float* W1   = (const float*)d_in[3];
    const float* b1   = (const float*)d_in[4];
    const float* W2   = (const float*)d_in[5];
    const float* b2   = (const float*)d_in[6];
    const float* Wf1  = (const float*)d_in[7];
    const float* bf1  = (const float*)d_in[8];
    const float* Wf2  = (const float*)d_in[9];
    const float* bf2  = (const float*)d_in[10];
    float* out = (float*)d_out;

    char* p = (char*)d_ws;
    _Float16* xwh  = (_Float16*)p;  p += (size_t)N_NODES * HDIM * 2;   // [N][64] f16
    _Float16* h1b  = (_Float16*)p;  p += (size_t)N_NODES * HDIM * 2;
    _Float16* h2b  = (_Float16*)p;  p += (size_t)N_NODES * HDIM * 2;
    _Float16* Wt1  = (_Float16*)p;  p += (size_t)F_IN * HDIM * 2;
    _Float16* Wt2  = (_Float16*)p;  p += (size_t)HDIM * HDIM * 2;
    float*  dinv   = (float*)p;     p += (size_t)N_NODES * 4;
    int*    row    = (int*)p;       p += (size_t)(N_NODES + 1) * 4;
    int*    csr    = (int*)p;       p += (size_t)N_EDGES * 4;
    int*    bTot   = (int*)p;       p += 512 * 4;
    int*    stage  = (int*)p;       p += (size_t)NBUCK * BCAP * 4;

    twt_k<<<1, 256, 0, stream>>>(W1, W2, Wt1, Wt2, bTot);
    pass1_k<<<N_P1, 256, 0, stream>>>(src, dst, bTot, stage);
    pass2_k<<<NBUCK, 256, 0, stream>>>(stage, bTot, row, dinv, csr);

    xw1_k<<<(N_NODES + 63) / 64, 256, 0, stream>>>(x, Wt1, dinv, xwh);
    gather_k<<<N_NODES / 4, 256, 0, stream>>>(xwh, row, csr, dinv, b1, h1b);
    conv2_k<<<(N_NODES + 63) / 64, 256, 0, stream>>>(h1b, Wt2, dinv, xwh);
    gather_k<<<N_NODES / 4, 256, 0, stream>>>(xwh, row, csr, dinv, b2, h2b);

    poolmlp_k<<<N_GRAPHS, 256, 0, stream>>>(h2b, batch, Wf1, bf1, Wf2, bf2, out);
}

// Round 9
// 183.975 us; speedup vs baseline: 1.1508x; 1.1508x over previous
//
#include <hip/hip_runtime.h>
#include <hip/hip_fp16.h>

#define N_NODES 50000
#define N_EDGES 800000
#define N_GRAPHS 512
#define F_IN 128
#define HDIM 64
#define NBUCK 196            // ceil(50000/256) buckets of 256 nodes
#define BCAP 5120            // per-bucket staging cap (avg 4082)
#define EPB 4096             // edges per pass-1 block
#define N_P1 ((N_EDGES + EPB - 1) / EPB)   // 196
#define MAXPER 20            // BCAP/256

typedef _Float16 half8 __attribute__((ext_vector_type(8)));
typedef float f32x4 __attribute__((ext_vector_type(4)));

__device__ inline int wave_incl_scan(int v, int lane) {
    #pragma unroll
    for (int off = 1; off < 64; off <<= 1) {
        int u = __shfl_up(v, off);
        if (lane >= off) v += u;
    }
    return v;
}

// ---------------- prep: zero bTot/pooled, transpose W1,W2 to [col][k] f16 ----------------
__global__ __launch_bounds__(256) void prep_k(const float* __restrict__ W1, const float* __restrict__ W2,
                                              _Float16* __restrict__ Wt1, _Float16* __restrict__ Wt2,
                                              int* __restrict__ bTot, float* __restrict__ pooled) {
    int t = threadIdx.x;
    int id = blockIdx.x * 256 + t;
    if (blockIdx.x == 0) bTot[t] = 0;
    pooled[id] = 0.f;                       // 64*256 = 16384
    pooled[id + 16384] = 0.f;               // total 32768 = 512*64
    if (id < F_IN * HDIM) { int k = id >> 6, c = id & 63; Wt1[c * F_IN + k] = (_Float16)W1[id]; }
    if (id < HDIM * HDIM) { int k = id >> 6, c = id & 63; Wt2[c * HDIM + k] = (_Float16)W2[id]; }
}

// ---------------- pass 1: bin edges by dst bucket; LDS counting sort -> coalesced writes ----------------
__global__ __launch_bounds__(256) void pass1_k(const int* __restrict__ src, const int* __restrict__ dst,
                                               int* __restrict__ bucketTot, int* __restrict__ stage) {
    __shared__ int cnt[256];
    __shared__ int pfE[256];
    __shared__ int goff[256];
    __shared__ int wsum[4];
    __shared__ int totS;
    __shared__ int lpk[EPB];
    __shared__ unsigned char bkn[EPB];
    int t = threadIdx.x;
    cnt[t] = 0;
    __syncthreads();
    int base = blockIdx.x * EPB + t * 16;
    int packed[16], bk[16], rk[16];
    bool full = (blockIdx.x + 1) * EPB <= N_EDGES;
    if (full) {
        const int4* s4 = (const int4*)(src + base);
        const int4* d4 = (const int4*)(dst + base);
        #pragma unroll
        for (int q = 0; q < 4; ++q) {
            int4 sv = s4[q], dv = d4[q];
            int ss[4] = {sv.x, sv.y, sv.z, sv.w};
            int dd[4] = {dv.x, dv.y, dv.z, dv.w};
            #pragma unroll
            for (int jj = 0; jj < 4; ++jj) {
                int b = dd[jj] >> 8;
                rk[q * 4 + jj] = atomicAdd(&cnt[b], 1);
                bk[q * 4 + jj] = b;
                packed[q * 4 + jj] = ss[jj] | ((dd[jj] & 255) << 16);
            }
        }
    } else {
        #pragma unroll
        for (int k = 0; k < 16; ++k) {
            int e = base + k;
            if (e < N_EDGES) {
                int d = dst[e];
                int b = d >> 8;
                rk[k] = atomicAdd(&cnt[b], 1);
                bk[k] = b;
                packed[k] = src[e] | ((d & 255) << 16);
            } else bk[k] = -1;
        }
    }
    __syncthreads();
    int cv = cnt[t];
    int w = t >> 6, lane = t & 63;
    int inc = wave_incl_scan(cv, lane);
    if (lane == 63) wsum[w] = inc;
    __syncthreads();
    if (w == 0) {
        int x = (lane < 4) ? wsum[lane] : 0;
        x = wave_incl_scan(x, lane);
        if (lane < 4) wsum[lane] = x;
    }
    __syncthreads();
    int excl = inc - cv + ((w > 0) ? wsum[w - 1] : 0);
    pfE[t] = excl;
    if (t == 255) totS = excl + cv;
    if (cv > 0) goff[t] = atomicAdd(&bucketTot[t], cv);
    __syncthreads();
    #pragma unroll
    for (int k = 0; k < 16; ++k) {
        if (bk[k] >= 0) {
            int b = bk[k];
            int p = pfE[b] + rk[k];
            lpk[p] = packed[k];
            bkn[p] = (unsigned char)b;
        }
    }
    __syncthreads();
    int tot = totS;
    for (int i = t; i < tot; i += 256) {
        int b = bkn[i];
        int local = i - pfE[b];
        stage[b * BCAP + goff[b] + local] = lpk[i];
    }
}

// ---------------- pass 2: per-bucket LDS counting sort -> csr(u16), row, dinv ----------------
__global__ __launch_bounds__(256) void pass2_k(const int* __restrict__ stage, const int* __restrict__ bucketTot,
                                               int* __restrict__ row, float* __restrict__ dinv,
                                               unsigned short* __restrict__ csr) {
    __shared__ int cnt[256];
    __shared__ int pf[256];
    __shared__ int wsum[4];
    __shared__ int baseS;
    __shared__ int lcsr[BCAP];
    int b = blockIdx.x, t = threadIdx.x;
    int tot = bucketTot[b];
    int w = t >> 6, lane = t & 63;
    // exclusive scan of bucketTot to get this block's base
    {
        int v = (t < NBUCK) ? bucketTot[t] : 0;
        int inc = wave_incl_scan(v, lane);
        if (lane == 63) wsum[w] = inc;
        __syncthreads();
        if (w == 0) {
            int x = (lane < 4) ? wsum[lane] : 0;
            x = wave_incl_scan(x, lane);
            if (lane < 4) wsum[lane] = x;
        }
        __syncthreads();
        if (t == b) baseS = inc - v + ((w > 0) ? wsum[w - 1] : 0);
    }
    if (b == 0 && t == 0) row[N_NODES] = N_EDGES;
    cnt[t] = 0; __syncthreads();
    int myp[MAXPER], myr[MAXPER];
    #pragma unroll
    for (int k = 0; k < MAXPER; ++k) {
        int i = t + k * 256;
        if (i < tot) {
            int p = stage[b * BCAP + i];
            int loc = (p >> 16) & 255;
            myp[k] = p;
            myr[k] = atomicAdd(&cnt[loc], 1);
        } else myp[k] = -1;
    }
    __syncthreads();
    int cv = cnt[t];
    int inc = wave_incl_scan(cv, lane);
    if (lane == 63) wsum[w] = inc;
    __syncthreads();
    if (w == 0) {
        int x = (lane < 4) ? wsum[lane] : 0;
        x = wave_incl_scan(x, lane);
        if (lane < 4) wsum[lane] = x;
    }
    __syncthreads();
    int excl = inc - cv + ((w > 0) ? wsum[w - 1] : 0);
    pf[t] = excl;
    __syncthreads();
    int base = baseS;
    int node = (b << 8) + t;
    if (node < N_NODES) {
        row[node] = base + excl;
        dinv[node] = rsqrtf((float)cv + 1.0f);
    }
    #pragma unroll
    for (int k = 0; k < MAXPER; ++k) {
        if (myp[k] >= 0) {
            int loc = (myp[k] >> 16) & 255;
            lcsr[pf[loc] + myr[k]] = myp[k] & 0xFFFF;
        }
    }
    __syncthreads();
    for (int i = t; i < tot; i += 256) csr[base + i] = (unsigned short)lcsr[i];
}

// ---------------- xw1 = (x @ W1) * dinv -> f16 interleaved [N][64], via MFMA ----------------
__global__ __launch_bounds__(256) void xw1_k(const float* __restrict__ x, const _Float16* __restrict__ Wt1,
                                             const float* __restrict__ dinv, _Float16* __restrict__ xwh) {
    __shared__ _Float16 xs[64][136];   // [node][k], pad 8
    __shared__ _Float16 wt[64][136];   // [col][k]
    __shared__ _Float16 outt[64][72];  // [node][col]
    int t = threadIdx.x;
    int row0 = blockIdx.x * 64;
    const float4* x4 = (const float4*)x;
    #pragma unroll
    for (int i = 0; i < 8; ++i) {
        int m = t + i * 256;           // 64 rows x 32 float4
        int n = m >> 5, k4 = m & 31;
        int gn = row0 + n;
        float4 v = make_float4(0.f, 0.f, 0.f, 0.f);
        if (gn < N_NODES) v = x4[gn * 32 + k4];
        _Float16* p = &xs[n][k4 * 4];
        p[0] = (_Float16)v.x; p[1] = (_Float16)v.y; p[2] = (_Float16)v.z; p[3] = (_Float16)v.w;
    }
    const uint4* wt4 = (const uint4*)Wt1;
    #pragma unroll
    for (int i = 0; i < 4; ++i) {
        int m = t + i * 256;           // 64 cols x 16 uint4
        int c = m >> 4, k8 = m & 15;
        *(uint4*)&wt[c][k8 * 8] = wt4[m];
    }
    __syncthreads();
    int w = t >> 6, lane = t & 63, r = lane & 15, q = lane >> 4;
    half8 a[4];
    #pragma unroll
    for (int kk = 0; kk < 4; ++kk) a[kk] = *(const half8*)&xs[w * 16 + r][kk * 32 + q * 8];
    float dv[4];
    #pragma unroll
    for (int reg = 0; reg < 4; ++reg) {
        int n = row0 + w * 16 + q * 4 + reg;
        dv[reg] = (n < N_NODES) ? dinv[n] : 0.f;
    }
    #pragma unroll
    for (int ct = 0; ct < 4; ++ct) {
        f32x4 acc = {0.f, 0.f, 0.f, 0.f};
        #pragma unroll
        for (int kk = 0; kk < 4; ++kk) {
            half8 b = *(const half8*)&wt[ct * 16 + r][kk * 32 + q * 8];
            acc = __builtin_amdgcn_mfma_f32_16x16x32_f16(a[kk], b, acc, 0, 0, 0);
        }
        #pragma unroll
        for (int reg = 0; reg < 4; ++reg)
            outt[w * 16 + q * 4 + reg][ct * 16 + r] = (_Float16)(acc[reg] * dv[reg]);
    }
    __syncthreads();
    #pragma unroll
    for (int i = 0; i < 2; ++i) {
        int m = t + i * 256;           // 64 rows x 8 col-octets
        int n = m >> 3, c8 = m & 7;
        int gn = row0 + n;
        if (gn < N_NODES) {
            uint4 v = *(const uint4*)&outt[n][c8 * 8];
            ((uint4*)xwh)[gn * 8 + c8] = v;
        }
    }
}

// ---------------- xw2 = (h1 @ W2) * dinv -> f16 interleaved, via MFMA ----------------
__global__ __launch_bounds__(256) void conv2_k(const _Float16* __restrict__ h1, const _Float16* __restrict__ Wt2,
                                               const float* __restrict__ dinv, _Float16* __restrict__ xwh) {
    __shared__ _Float16 hs[64][72];
    __shared__ _Float16 wt[64][72];
    __shared__ _Float16 outt[64][72];
    int t = threadIdx.x;
    int row0 = blockIdx.x * 64;
    const uint4* h8 = (const uint4*)h1;
    #pragma unroll
    for (int i = 0; i < 2; ++i) {
        int m = t + i * 256;
        int n = m >> 3, k8 = m & 7;
        int gn = row0 + n;
        uint4 v = make_uint4(0u, 0u, 0u, 0u);
        if (gn < N_NODES) v = h8[gn * 8 + k8];
        *(uint4*)&hs[n][k8 * 8] = v;
    }
    const uint4* wt4 = (const uint4*)Wt2;
    #pragma unroll
    for (int i = 0; i < 2; ++i) {
        int m = t + i * 256;           // 64 cols x 8 uint4
        int c = m >> 3, k8 = m & 7;
        *(uint4*)&wt[c][k8 * 8] = wt4[m];
    }
    __syncthreads();
    int w = t >> 6, lane = t & 63, r = lane & 15, q = lane >> 4;
    half8 a0 = *(const half8*)&hs[w * 16 + r][q * 8];
    half8 a1 = *(const half8*)&hs[w * 16 + r][32 + q * 8];
    float dv[4];
    #pragma unroll
    for (int reg = 0; reg < 4; ++reg) {
        int n = row0 + w * 16 + q * 4 + reg;
        dv[reg] = (n < N_NODES) ? dinv[n] : 0.f;
    }
    #pragma unroll
    for (int ct = 0; ct < 4; ++ct) {
        f32x4 acc = {0.f, 0.f, 0.f, 0.f};
        half8 b0 = *(const half8*)&wt[ct * 16 + r][q * 8];
        half8 b1 = *(const half8*)&wt[ct * 16 + r][32 + q * 8];
        acc = __builtin_amdgcn_mfma_f32_16x16x32_f16(a0, b0, acc, 0, 0, 0);
        acc = __builtin_amdgcn_mfma_f32_16x16x32_f16(a1, b1, acc, 0, 0, 0);
        #pragma unroll
        for (int reg = 0; reg < 4; ++reg)
            outt[w * 16 + q * 4 + reg][ct * 16 + r] = (_Float16)(acc[reg] * dv[reg]);
    }
    __syncthreads();
    #pragma unroll
    for (int i = 0; i < 2; ++i) {
        int m = t + i * 256;
        int n = m >> 3, c8 = m & 7;
        int gn = row0 + n;
        if (gn < N_NODES) {
            uint4 v = *(const uint4*)&outt[n][c8 * 8];
            ((uint4*)xwh)[gn * 8 + c8] = v;
        }
    }
}

// ---------------- gather helpers ----------------
__device__ inline void acc8(uint4 v, float* a) {
    float2 f;
    f = __half22float2(__builtin_bit_cast(__half2, v.x)); a[0] += f.x; a[1] += f.y;
    f = __half22float2(__builtin_bit_cast(__half2, v.y)); a[2] += f.x; a[3] += f.y;
    f = __half22float2(__builtin_bit_cast(__half2, v.z)); a[4] += f.x; a[5] += f.y;
    f = __half22float2(__builtin_bit_cast(__half2, v.w)); a[6] += f.x; a[7] += f.y;
}

// ---------------- gather1: h1[d] = relu(dinv[d]*(sum xwh[s] + xwh[d]) + b1) -> f16 ----------------
__global__ __launch_bounds__(256) void gather_k(const _Float16* __restrict__ xwh, const int* __restrict__ row,
                                                const unsigned short* __restrict__ csr, const float* __restrict__ dinv,
                                                const float* __restrict__ bias, _Float16* __restrict__ hout) {
    int t = threadIdx.x;
    int node = blockIdx.x * 4 + (t >> 6);
    int lane = t & 63;
    int fq = lane & 7, eslot = lane >> 3;   // 8 feature quads x 8 edge slots
    const uint4* xw4 = (const uint4*)xwh;
    float a[8];
    #pragma unroll
    for (int k = 0; k < 8; ++k) a[k] = 0.f;
    if (eslot == 0) acc8(xw4[node * 8 + fq], a);   // self-loop
    int j = row[node] + eslot, jend = row[node + 1];
    for (; j + 8 < jend; j += 16) {
        int s0 = csr[j], s1 = csr[j + 8];
        uint4 v0 = xw4[s0 * 8 + fq];
        uint4 v1 = xw4[s1 * 8 + fq];
        acc8(v0, a); acc8(v1, a);
    }
    if (j < jend) acc8(xw4[csr[j] * 8 + fq], a);
    #pragma unroll
    for (int k = 0; k < 8; ++k) {
        a[k] += __shfl_xor(a[k], 8);
        a[k] += __shfl_xor(a[k], 16);
        a[k] += __shfl_xor(a[k], 32);
    }
    if (eslot == 0) {
        float dd = dinv[node];
        const float4* b4 = (const float4*)bias;
        float4 bl = b4[fq * 2], bh = b4[fq * 2 + 1];
        float r0 = fmaxf(a[0] * dd + bl.x, 0.f), r1 = fmaxf(a[1] * dd + bl.y, 0.f);
        float r2 = fmaxf(a[2] * dd + bl.z, 0.f), r3 = fmaxf(a[3] * dd + bl.w, 0.f);
        float r4 = fmaxf(a[4] * dd + bh.x, 0.f), r5 = fmaxf(a[5] * dd + bh.y, 0.f);
        float r6 = fmaxf(a[6] * dd + bh.z, 0.f), r7 = fmaxf(a[7] * dd + bh.w, 0.f);
        __half2 p0 = __float22half2_rn(make_float2(r0, r1));
        __half2 p1 = __float22half2_rn(make_float2(r2, r3));
        __half2 p2 = __float22half2_rn(make_float2(r4, r5));
        __half2 p3 = __float22half2_rn(make_float2(r6, r7));
        uint4 o;
        o.x = __builtin_bit_cast(unsigned int, p0);
        o.y = __builtin_bit_cast(unsigned int, p1);
        o.z = __builtin_bit_cast(unsigned int, p2);
        o.w = __builtin_bit_cast(unsigned int, p3);
        ((uint4*)hout)[node * 8 + fq] = o;
    }
}

// ---------------- gather2 + pool: pooled[batch[d]] += relu(dinv[d]*(...)+b2) ----------------
__global__ __launch_bounds__(256) void gather2pool_k(const _Float16* __restrict__ xwh, const int* __restrict__ row,
                                                     const unsigned short* __restrict__ csr, const float* __restrict__ dinv,
                                                     const float* __restrict__ bias, const int* __restrict__ batch,
                                                     float* __restrict__ pooled) {
    __shared__ float hacc[4][64];
    __shared__ int gid[4];
    int t = threadIdx.x;
    int wv = t >> 6;
    int node = blockIdx.x * 4 + wv;
    int lane = t & 63;
    int fq = lane & 7, eslot = lane >> 3;
    const uint4* xw4 = (const uint4*)xwh;
    float a[8];
    #pragma unroll
    for (int k = 0; k < 8; ++k) a[k] = 0.f;
    if (eslot == 0) acc8(xw4[node * 8 + fq], a);
    int j = row[node] + eslot, jend = row[node + 1];
    for (; j + 8 < jend; j += 16) {
        int s0 = csr[j], s1 = csr[j + 8];
        uint4 v0 = xw4[s0 * 8 + fq];
        uint4 v1 = xw4[s1 * 8 + fq];
        acc8(v0, a); acc8(v1, a);
    }
    if (j < jend) acc8(xw4[csr[j] * 8 + fq], a);
    #pragma unroll
    for (int k = 0; k < 8; ++k) {
        a[k] += __shfl_xor(a[k], 8);
        a[k] += __shfl_xor(a[k], 16);
        a[k] += __shfl_xor(a[k], 32);
    }
    if (lane == 0) gid[wv] = batch[node];
    if (eslot == 0) {
        float dd = dinv[node];
        const float4* b4 = (const float4*)bias;
        float4 bl = b4[fq * 2], bh = b4[fq * 2 + 1];
        hacc[wv][fq * 8 + 0] = fmaxf(a[0] * dd + bl.x, 0.f);
        hacc[wv][fq * 8 + 1] = fmaxf(a[1] * dd + bl.y, 0.f);
        hacc[wv][fq * 8 + 2] = fmaxf(a[2] * dd + bl.z, 0.f);
        hacc[wv][fq * 8 + 3] = fmaxf(a[3] * dd + bl.w, 0.f);
        hacc[wv][fq * 8 + 4] = fmaxf(a[4] * dd + bh.x, 0.f);
        hacc[wv][fq * 8 + 5] = fmaxf(a[5] * dd + bh.y, 0.f);
        hacc[wv][fq * 8 + 6] = fmaxf(a[6] * dd + bh.z, 0.f);
        hacc[wv][fq * 8 + 7] = fmaxf(a[7] * dd + bh.w, 0.f);
    }
    __syncthreads();
    if (t < 64) {
        int g0 = gid[0];
        if (gid[1] == g0 && gid[2] == g0 && gid[3] == g0) {
            float s = hacc[0][t] + hacc[1][t] + hacc[2][t] + hacc[3][t];
            atomicAdd(&pooled[g0 * 64 + t], s);
        } else {
            #pragma unroll
            for (int w2 = 0; w2 < 4; ++w2) atomicAdd(&pooled[gid[w2] * 64 + t], hacc[w2][t]);
        }
    }
}

// ---------------- final MLP (divides pooled sum by count) ----------------
__device__ inline int lower_bound_i(const int* __restrict__ a, int n, int v) {
    int lo = 0, hi = n;
    while (lo < hi) { int m = (lo + hi) >> 1; if (a[m] < v) lo = m + 1; else hi = m; }
    return lo;
}

__global__ __launch_bounds__(128) void mlp_k(const float* __restrict__ pooled, const int* __restrict__ batch,
                                             const float* __restrict__ Wf1, const float* __restrict__ bf1,
                                             const float* __restrict__ Wf2, const float* __restrict__ bf2,
                                             float* __restrict__ out) {
    __shared__ int se[2];
    __shared__ float ps[64];
    __shared__ float wsum[2];
    int g = blockIdx.x, t = threadIdx.x;
    if (t == 0) { se[0] = lower_bound_i(batch, N_NODES, g); se[1] = lower_bound_i(batch, N_NODES, g + 1); }
    __syncthreads();
    int c = se[1] - se[0];
    float inv = 1.0f / (float)max(c, 1);
    if (t < 64) ps[t] = pooled[g * 64 + t] * inv;
    __syncthreads();
    float a2 = bf1[t];
    #pragma unroll 8
    for (int k = 0; k < HDIM; ++k) a2 += ps[k] * Wf1[k * 128 + t];
    float v = fmaxf(a2, 0.f) * Wf2[t];
    #pragma unroll
    for (int off = 32; off > 0; off >>= 1) v += __shfl_down(v, off);
    if ((t & 63) == 0) wsum[t >> 6] = v;
    __syncthreads();
    if (t == 0) out[g] = wsum[0] + wsum[1] + bf2[0];
}

extern "C" void kernel_launch(void* const* d_in, const int* in_sizes, int n_in,
                              void* d_out, int out_size, void* d_ws, size_t ws_size,
                              hipStream_t stream) {
    const float* x    = (const float*)d_in[0];
    const int*   ei   = (const int*)d_in[1];
    const int*   src  = ei;
    const int*   dst  = ei + N_EDGES;
    const int*   batch= (const int*)d_in[2];
    const float* W1   = (const float*)d_in[3];
    const float* b1   = (const float*)d_in[4];
    const float* W2   = (const float*)d_in[5];
    const float* b2   = (const float*)d_in[6];
    const float* Wf1  = (const float*)d_in[7];
    const float* bf1  = (const float*)d_in[8];
    const float* Wf2  = (const float*)d_in[9];
    const float* bf2  = (const float*)d_in[10];
    float* out = (float*)d_out;

    char* p = (char*)d_ws;
    _Float16* xwh  = (_Float16*)p;  p += (size_t)N_NODES * HDIM * 2;   // [N][64] f16
    _Float16* h1b  = (_Float16*)p;  p += (size_t)N_NODES * HDIM * 2;
    _Float16* Wt1  = (_Float16*)p;  p += (size_t)F_IN * HDIM * 2;
    _Float16* Wt2  = (_Float16*)p;  p += (size_t)HDIM * HDIM * 2;
    float*  dinv   = (float*)p;     p += (size_t)N_NODES * 4;
    float*  pooled = (float*)p;     p += (size_t)N_GRAPHS * HDIM * 4;
    int*    row    = (int*)p;       p += (size_t)(N_NODES + 1) * 4;
    unsigned short* csr = (unsigned short*)p; p += (size_t)N_EDGES * 2;
    int*    bTot   = (int*)p;       p += 256 * 4;
    int*    stage  = (int*)p;       p += (size_t)NBUCK * BCAP * 4;

    prep_k<<<64, 256, 0, stream>>>(W1, W2, Wt1, Wt2, bTot, pooled);
    pass1_k<<<N_P1, 256, 0, stream>>>(src, dst, bTot, stage);
    pass2_k<<<NBUCK, 256, 0, stream>>>(stage, bTot, row, dinv, csr);

    xw1_k<<<(N_NODES + 63) / 64, 256, 0, stream>>>(x, Wt1, dinv, xwh);
    gather_k<<<N_NODES / 4, 256, 0, stream>>>(xwh, row, csr, dinv, b1, h1b);
    conv2_k<<<(N_NODES + 63) / 64, 256, 0, stream>>>(h1b, Wt2, dinv, xwh);
    gather2pool_k<<<N_NODES / 4, 256, 0, stream>>>(xwh, row, csr, dinv, b2, batch, pooled);

    mlp_k<<<N_GRAPHS, 128, 0, stream>>>(pooled, batch, Wf1, bf1, Wf2, bf2, out);
}